// Round 6
// baseline (65.963 us; speedup 1.0000x reference)
//
#include <hip/hip_runtime.h>
#include <hip/hip_bf16.h>

typedef unsigned short u16;
typedef short s16x8 __attribute__((ext_vector_type(8)));
typedef u16 u16x8 __attribute__((ext_vector_type(8)));
typedef unsigned int u32x4 __attribute__((ext_vector_type(4)));
typedef float f32x4 __attribute__((ext_vector_type(4)));

struct cplx { float x, y; };

#define L_SEQ 2048
#define HID 512
#define NST 64

// ---------------- device scratch (fully rewritten every call) ----------------
__device__ __align__(16) cplx g_khat[L_SEQ];        // k̂_j at 2048 roots of unity
__device__ __align__(16) float g_k[L_SEQ];
__device__ __align__(16) u16 g_Xt[HID * L_SEQ];     // bf16 X^T  [h][l]
__device__ __align__(16) u16 g_W1[HID * HID];       // bf16 [n][k]
__device__ __align__(16) u16 g_W2[HID * HID];
__device__ __align__(16) u16 g_H[L_SEQ * HID];      // bf16 gelu(conv out) [l][h]

__device__ __forceinline__ u16 f2bf(float f) {
    union { __hip_bfloat16 h; u16 u; } cv;
    cv.h = __float2bfloat16(f);
    return cv.u;
}

// ---------------- fused: X transpose + W converts + khat ----------------
// blocks 0..255: X -> bf16 X^T ; 256..767: W1/W2 ; 768..775: khat
// k̂_j = 2 conj(C)^T [ (2/Δ)(1-ω)I - (1+ω)A ]^{-1} B ; A = diag(Λ) - P P^H (Woodbury)
__global__ __launch_bounds__(256) void fused_convert(
    const float* x, const float* w1, const float* w2,
    const float* lre, const float* lim, const float* pre, const float* pim,
    const float* bre, const float* bim, const float* cre, const float* cim,
    const float* lstep) {
    __shared__ float tile[64][65];
    __shared__ float sLre[NST], sLim[NST], sPre[NST], sPim[NST];
    __shared__ float sBre[NST], sBim[NST], sCre[NST], sCim[NST];
    int b = blockIdx.x, tid = threadIdx.x;
    if (b < 256) {
        int lt = b >> 3, ht = b & 7;
#pragma unroll
        for (int i = 0; i < 4; i++) {
            int idx = i * 256 + tid;        // 1024 float4
            int r = idx >> 4, c4 = idx & 15;
            f32x4 v = *(const f32x4*)&x[(lt * 64 + r) * HID + ht * 64 + c4 * 4];
            tile[r][c4 * 4 + 0] = v.x;
            tile[r][c4 * 4 + 1] = v.y;
            tile[r][c4 * 4 + 2] = v.z;
            tile[r][c4 * 4 + 3] = v.w;
        }
        __syncthreads();
#pragma unroll
        for (int i = 0; i < 2; i++) {
            int idx = i * 256 + tid;        // 512 u16x8
            int rr = idx >> 3, c8 = idx & 7;
            u16x8 v;
#pragma unroll
            for (int q = 0; q < 8; q++) v[q] = f2bf(tile[c8 * 8 + q][rr]);
            *(u16x8*)&g_Xt[(ht * 64 + rr) * L_SEQ + lt * 64 + c8 * 8] = v;
        }
    } else if (b < 768) {
        int t = (b - 256) * 256 + tid;  // 131072
        const float* src = (t < 65536) ? w1 : w2;
        u16* dst = (t < 65536) ? g_W1 : g_W2;
        int idx = (t < 65536) ? t : (t - 65536);
        float4 v = ((const float4*)src)[idx];
        unsigned long long pk = (unsigned long long)f2bf(v.x) |
                                ((unsigned long long)f2bf(v.y) << 16) |
                                ((unsigned long long)f2bf(v.z) << 32) |
                                ((unsigned long long)f2bf(v.w) << 48);
        ((unsigned long long*)dst)[idx] = pk;
    } else {
        if (tid < NST) {
            sLre[tid] = lre[tid]; sLim[tid] = lim[tid];
            sPre[tid] = pre[tid]; sPim[tid] = pim[tid];
            sBre[tid] = bre[tid]; sBim[tid] = bim[tid];
            sCre[tid] = cre[tid]; sCim[tid] = cim[tid];
        }
        __syncthreads();
        int j = (b - 768) * 256 + tid;  // 0..2047
        float tdt = 2.0f * __expf(-lstep[0]);          // 2/step
        float th = 0.00306796157577128245f * j;        // 2*pi/2048 * j
        float sn, cs;
        __sincosf(th, &sn, &cs);
        float aRe = tdt * (1.f - cs), aIm = tdt * sn;  // (2/dt)(1-w)
        float bRe = 1.f + cs, bIm = -sn;               // beta = 1+w
        float cBx = 0.f, cBy = 0.f, cPx = 0.f, cPy = 0.f;
        float pBx = 0.f, pBy = 0.f, pPx = 0.f, pPy = 0.f;
#pragma unroll 8
        for (int n = 0; n < NST; n++) {
            float Lre = sLre[n], Lim = sLim[n];
            float Dre = aRe - (bRe * Lre - bIm * Lim);
            float Dim = aIm - (bRe * Lim + bIm * Lre);
            float inv = 1.f / (Dre * Dre + Dim * Dim);
            float eRe = Dre * inv, eIm = -Dim * inv;   // 1/D_n
            float cRe = sCre[n], cIm = -sCim[n];
            float t1Re = cRe * eRe - cIm * eIm, t1Im = cRe * eIm + cIm * eRe;
            float qRe = sPre[n], qIm = -sPim[n];
            float t2Re = qRe * eRe - qIm * eIm, t2Im = qRe * eIm + qIm * eRe;
            float BRe = sBre[n], BIm = sBim[n], PRe = sPre[n], PIm = sPim[n];
            cBx += t1Re * BRe - t1Im * BIm; cBy += t1Re * BIm + t1Im * BRe;
            cPx += t1Re * PRe - t1Im * PIm; cPy += t1Re * PIm + t1Im * PRe;
            pBx += t2Re * BRe - t2Im * BIm; pBy += t2Re * BIm + t2Im * BRe;
            pPx += t2Re * PRe - t2Im * PIm; pPy += t2Re * PIm + t2Im * PRe;
        }
        float denx = 1.f + (bRe * pPx - bIm * pPy);
        float deny = (bRe * pPy + bIm * pPx);
        float bcPx = bRe * cPx - bIm * cPy;
        float bcPy = bRe * cPy + bIm * cPx;
        float numx = bcPx * pBx - bcPy * pBy;
        float numy = bcPx * pBy + bcPy * pBx;
        float dinv = 1.f / (denx * denx + deny * deny);
        float corx = (numx * denx + numy * deny) * dinv;
        float cory = (numy * denx - numx * deny) * dinv;
        g_khat[j] = { 2.f * (cBx - corx), 2.f * (cBy - cory) };
    }
}

// ---------------- Re(k_t) via Hermitian-symmetrized direct IDFT ----------------
__global__ __launch_bounds__(256) void k_ifft() {
    int tid = threadIdx.x;
    int l = tid & 63;
    int t = blockIdx.x * 4 + (tid >> 6);  // 512 blocks x 4 waves = 2048 t's
    float acc = 0.f;
#pragma unroll
    for (int i = 0; i < 16; i++) {
        int j = l + 64 * i;  // 0..1023
        cplx a = g_khat[j];
        cplx b = g_khat[(2048 - j) & 2047];
        float re = 0.5f * (a.x + b.x);
        float im = 0.5f * (a.y - b.y);
        int idx = (j * t) & 2047;
        float s, c;
        __sincosf(0.00306796157577128245f * idx, &s, &c);
        float wgt = (j == 0) ? 1.f : 2.f;
        acc += wgt * (re * c - im * s);
    }
    if (l == 0) acc += (1 - 2 * (t & 1)) * g_khat[1024].x;
#pragma unroll
    for (int off = 1; off < 64; off <<= 1) acc += __shfl_xor(acc, off);
    if (l == 0) g_k[t] = acc * (1.f / 2048.f);
}

// ---------------- conv GEMM: Y = T @ X, T built from k in LDS (Toeplitz) ----------------
__global__ __launch_bounds__(256) void conv_gemm() {
    __shared__ __align__(16) float kLds[L_SEQ];
    __shared__ __align__(16) u16 As[64 * 64];
    __shared__ __align__(16) u16 Bs[64 * 64];
    int tid = threadIdx.x, l = tid & 63, w = tid >> 6;
    int wm = w >> 1, wn = w & 1;
    int bm = blockIdx.x >> 3, bn = blockIdx.x & 7;  // 32 x 8
    f32x4 acc[2][2] = {};
    int nkb = bm + 1;  // triangular
    int row0 = tid >> 3, kc0 = tid & 7;
    int row1 = (256 + tid) >> 3, kc1 = tid & 7;
    const u16* brow0 = &g_Xt[(bn * 64 + row0) * L_SEQ + kc0 * 8];
    const u16* brow1 = &g_Xt[(bn * 64 + row1) * L_SEQ + kc1 * 8];
    int sa0 = row0 * 8 + (kc0 ^ (row0 & 7));
    int sa1 = row1 * 8 + (kc1 ^ (row1 & 7));
    // preload whole k into LDS (8 KB)
#pragma unroll
    for (int i = 0; i < 2; i++)
        ((f32x4*)kLds)[i * 256 + tid] = ((const f32x4*)g_k)[i * 256 + tid];
    // depth-2 B prefetch ring
    u32x4 rbA0 = *(const u32x4*)brow0;
    u32x4 rbA1 = *(const u32x4*)brow1;
    u32x4 rbB0 = *(const u32x4*)(brow0 + 64);
    u32x4 rbB1 = *(const u32x4*)(brow1 + 64);

#define BUILD_AS(ROW, KC, SIDX)                                              \
    {                                                                        \
        int c0 = (KC) * 8;                                                   \
        u16x8 av;                                                            \
        _Pragma("unroll")                                                    \
        for (int q = 0; q < 8; q++) {                                        \
            int id = base + (ROW) - c0 - q;                                  \
            av[q] = (id >= 0) ? f2bf(kLds[id]) : (u16)0;                     \
        }                                                                    \
        *(u16x8*)&As[(SIDX) * 8] = av;                                       \
    }

#define CONV_COMPUTE                                                         \
    _Pragma("unroll")                                                        \
    for (int ks = 0; ks < 2; ks++) {                                         \
        s16x8 af[2], bf[2];                                                  \
        _Pragma("unroll")                                                    \
        for (int m = 0; m < 2; m++) {                                        \
            int row = wm * 32 + m * 16 + (l & 15);                           \
            int chunk = (ks * 4 + (l >> 4)) ^ (row & 7);                     \
            af[m] = *(const s16x8*)&As[row * 64 + chunk * 8];                \
        }                                                                    \
        _Pragma("unroll")                                                    \
        for (int n = 0; n < 2; n++) {                                        \
            int col = wn * 32 + n * 16 + (l & 15);                           \
            int chunk = (ks * 4 + (l >> 4)) ^ (col & 7);                     \
            bf[n] = *(const s16x8*)&Bs[col * 64 + chunk * 8];                \
        }                                                                    \
        _Pragma("unroll")                                                    \
        for (int m = 0; m < 2; m++)                                          \
            _Pragma("unroll")                                                \
            for (int n = 0; n < 2; n++)                                      \
                acc[m][n] = __builtin_amdgcn_mfma_f32_16x16x32_bf16(         \
                    af[m], bf[n], acc[m][n], 0, 0, 0);                       \
    }

#define CONV_STEP(R0, R1)                                                    \
    {                                                                        \
        __syncthreads();                                                     \
        ((u32x4*)Bs)[sa0] = R0;                                              \
        ((u32x4*)Bs)[sa1] = R1;                                              \
        int base = (bm - kb) * 64;                                           \
        BUILD_AS(row0, kc0, sa0);                                            \
        BUILD_AS(row1, kc1, sa1);                                            \
        if (kb + 2 < nkb) {                                                  \
            int k0n = (kb + 2) * 64;                                         \
            R0 = *(const u32x4*)(brow0 + k0n);                               \
            R1 = *(const u32x4*)(brow1 + k0n);                               \
        }                                                                    \
        __syncthreads();                                                     \
        CONV_COMPUTE;                                                        \
        kb++;                                                                \
    }

    int kb = 0;
    while (true) {
        CONV_STEP(rbA0, rbA1);
        if (kb >= nkb) break;
        CONV_STEP(rbB0, rbB1);
        if (kb >= nkb) break;
    }
#undef CONV_STEP
#undef CONV_COMPUTE
#undef BUILD_AS
#pragma unroll
    for (int m = 0; m < 2; m++)
#pragma unroll
        for (int n = 0; n < 2; n++)
#pragma unroll
            for (int r4 = 0; r4 < 4; r4++) {
                int row = bm * 64 + wm * 32 + m * 16 + (l >> 4) * 4 + r4;
                int col = bn * 64 + wn * 32 + n * 16 + (l & 15);
                float y = acc[m][n][r4];
                float u = 1.5957691216057308f * (y + 0.044715f * y * y * y);
                float th = 1.f - 2.f / (__expf(u) + 1.f);
                g_H[row * HID + col] = f2bf(0.5f * y * (1.f + th));
            }
}

// ---------------- FFN: out = x + (H@W1^T + b1) * sigmoid(H@W2^T + b2) ----------------
__global__ __launch_bounds__(256) void ffn_gemm(const float* x, const float* b1,
                                                const float* b2, float* out) {
    __shared__ __align__(16) u16 As[64 * 64];
    __shared__ __align__(16) u16 B1s[64 * 64];
    __shared__ __align__(16) u16 B2s[64 * 64];
    int tid = threadIdx.x, l = tid & 63, w = tid >> 6;
    int wm = w >> 1, wn = w & 1;
    int bm = blockIdx.x >> 3, bn = blockIdx.x & 7;  // 32 x 8
    f32x4 acc1[2][2] = {}, acc2[2][2] = {};
    int row0 = tid >> 3, kc0 = tid & 7;
    int row1 = (256 + tid) >> 3;
    const u16* arow0 = &g_H[(bm * 64 + row0) * HID + kc0 * 8];
    const u16* arow1 = &g_H[(bm * 64 + row1) * HID + kc0 * 8];
    const u16* b1row0 = &g_W1[(bn * 64 + row0) * HID + kc0 * 8];
    const u16* b1row1 = &g_W1[(bn * 64 + row1) * HID + kc0 * 8];
    const u16* b2row0 = &g_W2[(bn * 64 + row0) * HID + kc0 * 8];
    const u16* b2row1 = &g_W2[(bn * 64 + row1) * HID + kc0 * 8];
    int sa0 = row0 * 8 + (kc0 ^ (row0 & 7));
    int sa1 = row1 * 8 + (kc0 ^ (row1 & 7));
    // depth-2 prefetch ring: sets [0] and [1]
    u32x4 rA0[2], rA1[2], rB10[2], rB11[2], rB20[2], rB21[2];
    rA0[0] = *(const u32x4*)arow0;           rA0[1] = *(const u32x4*)(arow0 + 64);
    rA1[0] = *(const u32x4*)arow1;           rA1[1] = *(const u32x4*)(arow1 + 64);
    rB10[0] = *(const u32x4*)b1row0;         rB10[1] = *(const u32x4*)(b1row0 + 64);
    rB11[0] = *(const u32x4*)b1row1;         rB11[1] = *(const u32x4*)(b1row1 + 64);
    rB20[0] = *(const u32x4*)b2row0;         rB20[1] = *(const u32x4*)(b2row0 + 64);
    rB21[0] = *(const u32x4*)b2row1;         rB21[1] = *(const u32x4*)(b2row1 + 64);
#pragma unroll
    for (int kb = 0; kb < 8; kb++) {
        const int cur = kb & 1;
        __syncthreads();
        ((u32x4*)As)[sa0] = rA0[cur];
        ((u32x4*)As)[sa1] = rA1[cur];
        ((u32x4*)B1s)[sa0] = rB10[cur];
        ((u32x4*)B1s)[sa1] = rB11[cur];
        ((u32x4*)B2s)[sa0] = rB20[cur];
        ((u32x4*)B2s)[sa1] = rB21[cur];
        if (kb + 2 < 8) {
            int k0 = (kb + 2) * 64;
            rA0[cur] = *(const u32x4*)(arow0 + k0);
            rA1[cur] = *(const u32x4*)(arow1 + k0);
            rB10[cur] = *(const u32x4*)(b1row0 + k0);
            rB11[cur] = *(const u32x4*)(b1row1 + k0);
            rB20[cur] = *(const u32x4*)(b2row0 + k0);
            rB21[cur] = *(const u32x4*)(b2row1 + k0);
        }
        __syncthreads();
#pragma unroll
        for (int ks = 0; ks < 2; ks++) {
            s16x8 af[2], b1f[2], b2f[2];
#pragma unroll
            for (int m = 0; m < 2; m++) {
                int row = wm * 32 + m * 16 + (l & 15);
                int chunk = (ks * 4 + (l >> 4)) ^ (row & 7);
                af[m] = *(const s16x8*)&As[row * 64 + chunk * 8];
            }
#pragma unroll
            for (int n = 0; n < 2; n++) {
                int col = wn * 32 + n * 16 + (l & 15);
                int chunk = (ks * 4 + (l >> 4)) ^ (col & 7);
                b1f[n] = *(const s16x8*)&B1s[col * 64 + chunk * 8];
                b2f[n] = *(const s16x8*)&B2s[col * 64 + chunk * 8];
            }
#pragma unroll
            for (int m = 0; m < 2; m++)
#pragma unroll
                for (int n = 0; n < 2; n++) {
                    acc1[m][n] = __builtin_amdgcn_mfma_f32_16x16x32_bf16(af[m], b1f[n], acc1[m][n], 0, 0, 0);
                    acc2[m][n] = __builtin_amdgcn_mfma_f32_16x16x32_bf16(af[m], b2f[n], acc2[m][n], 0, 0, 0);
                }
        }
    }
#pragma unroll
    for (int m = 0; m < 2; m++)
#pragma unroll
        for (int n = 0; n < 2; n++)
#pragma unroll
            for (int r4 = 0; r4 < 4; r4++) {
                int row = bm * 64 + wm * 32 + m * 16 + (l >> 4) * 4 + r4;
                int col = bn * 64 + wn * 32 + n * 16 + (l & 15);
                float g1 = acc1[m][n][r4] + b1[col];
                float g2 = acc2[m][n][r4] + b2[col];
                float sg = 1.f / (1.f + __expf(-g2));
                out[row * HID + col] = x[row * HID + col] + g1 * sg;
            }
}

extern "C" void kernel_launch(void* const* d_in, const int* in_sizes, int n_in,
                              void* d_out, int out_size, void* d_ws, size_t ws_size,
                              hipStream_t stream) {
    const float* x = (const float*)d_in[0];
    const float* lre = (const float*)d_in[1];
    const float* lim = (const float*)d_in[2];
    const float* pre = (const float*)d_in[3];
    const float* pim = (const float*)d_in[4];
    const float* bre = (const float*)d_in[5];
    const float* bim = (const float*)d_in[6];
    const float* cre = (const float*)d_in[7];
    const float* cim = (const float*)d_in[8];
    const float* lstep = (const float*)d_in[9];
    const float* w1 = (const float*)d_in[10];
    const float* b1 = (const float*)d_in[11];
    const float* w2 = (const float*)d_in[12];
    const float* b2 = (const float*)d_in[13];
    float* out = (float*)d_out;

    fused_convert<<<776, 256, 0, stream>>>(x, w1, w2, lre, lim, pre, pim,
                                           bre, bim, cre, cim, lstep);
    k_ifft<<<512, 256, 0, stream>>>();
    conv_gemm<<<256, 256, 0, stream>>>();
    ffn_gemm<<<256, 256, 0, stream>>>(x, b1, b2, out);
}

// Round 7
// 48.342 us; speedup vs baseline: 1.3645x; 1.3645x over previous
//
#include <hip/hip_runtime.h>
#include <hip/hip_bf16.h>

typedef unsigned short u16;
typedef short s16x8 __attribute__((ext_vector_type(8)));
typedef u16 u16x8 __attribute__((ext_vector_type(8)));
typedef unsigned int u32x4 __attribute__((ext_vector_type(4)));
typedef float f32x4 __attribute__((ext_vector_type(4)));

struct cplx { float x, y; };

#define L_SEQ 2048
#define HID 512
#define NST 64

// ---------------- device scratch (fully rewritten every call) ----------------
__device__ __align__(16) cplx g_khat[L_SEQ];        // k̂_j at 2048 roots of unity
__device__ __align__(16) float g_k[L_SEQ];
__device__ __align__(16) u16 g_Td[32 * 64 * 64];    // bf16 diagonal tiles: Td[d][r][c]=k[64d+r-c]
__device__ __align__(16) u16 g_Xt[HID * L_SEQ];     // bf16 X^T  [h][l]
__device__ __align__(16) u16 g_W1[HID * HID];       // bf16 [n][k]
__device__ __align__(16) u16 g_W2[HID * HID];
__device__ __align__(16) u16 g_H[L_SEQ * HID];      // bf16 gelu(conv out) [l][h]

__device__ __forceinline__ u16 f2bf(float f) {
    union { __hip_bfloat16 h; u16 u; } cv;
    cv.h = __float2bfloat16(f);
    return cv.u;
}

// ---------------- fused: X transpose + W converts + khat ----------------
// blocks 0..255: X -> bf16 X^T ; 256..767: W1/W2 ; 768..775: khat
// k̂_j = 2 conj(C)^T [ (2/Δ)(1-ω)I - (1+ω)A ]^{-1} B ; A = diag(Λ) - P P^H (Woodbury)
__global__ __launch_bounds__(256) void fused_convert(
    const float* x, const float* w1, const float* w2,
    const float* lre, const float* lim, const float* pre, const float* pim,
    const float* bre, const float* bim, const float* cre, const float* cim,
    const float* lstep) {
    __shared__ float tile[64][65];
    __shared__ float sLre[NST], sLim[NST], sPre[NST], sPim[NST];
    __shared__ float sBre[NST], sBim[NST], sCre[NST], sCim[NST];
    int b = blockIdx.x, tid = threadIdx.x;
    if (b < 256) {
        int lt = b >> 3, ht = b & 7;
#pragma unroll
        for (int i = 0; i < 4; i++) {
            int idx = i * 256 + tid;        // 1024 float4
            int r = idx >> 4, c4 = idx & 15;
            f32x4 v = *(const f32x4*)&x[(lt * 64 + r) * HID + ht * 64 + c4 * 4];
            tile[r][c4 * 4 + 0] = v.x;
            tile[r][c4 * 4 + 1] = v.y;
            tile[r][c4 * 4 + 2] = v.z;
            tile[r][c4 * 4 + 3] = v.w;
        }
        __syncthreads();
#pragma unroll
        for (int i = 0; i < 2; i++) {
            int idx = i * 256 + tid;        // 512 u16x8
            int rr = idx >> 3, c8 = idx & 7;
            u16x8 v;
#pragma unroll
            for (int q = 0; q < 8; q++) v[q] = f2bf(tile[c8 * 8 + q][rr]);
            *(u16x8*)&g_Xt[(ht * 64 + rr) * L_SEQ + lt * 64 + c8 * 8] = v;
        }
    } else if (b < 768) {
        int t = (b - 256) * 256 + tid;  // 131072
        const float* src = (t < 65536) ? w1 : w2;
        u16* dst = (t < 65536) ? g_W1 : g_W2;
        int idx = (t < 65536) ? t : (t - 65536);
        float4 v = ((const float4*)src)[idx];
        unsigned long long pk = (unsigned long long)f2bf(v.x) |
                                ((unsigned long long)f2bf(v.y) << 16) |
                                ((unsigned long long)f2bf(v.z) << 32) |
                                ((unsigned long long)f2bf(v.w) << 48);
        ((unsigned long long*)dst)[idx] = pk;
    } else {
        if (tid < NST) {
            sLre[tid] = lre[tid]; sLim[tid] = lim[tid];
            sPre[tid] = pre[tid]; sPim[tid] = pim[tid];
            sBre[tid] = bre[tid]; sBim[tid] = bim[tid];
            sCre[tid] = cre[tid]; sCim[tid] = cim[tid];
        }
        __syncthreads();
        int j = (b - 768) * 256 + tid;  // 0..2047
        float tdt = 2.0f * __expf(-lstep[0]);          // 2/step
        float th = 0.00306796157577128245f * j;        // 2*pi/2048 * j
        float sn, cs;
        __sincosf(th, &sn, &cs);
        float aRe = tdt * (1.f - cs), aIm = tdt * sn;  // (2/dt)(1-w)
        float bRe = 1.f + cs, bIm = -sn;               // beta = 1+w
        float cBx = 0.f, cBy = 0.f, cPx = 0.f, cPy = 0.f;
        float pBx = 0.f, pBy = 0.f, pPx = 0.f, pPy = 0.f;
#pragma unroll 8
        for (int n = 0; n < NST; n++) {
            float Lre = sLre[n], Lim = sLim[n];
            float Dre = aRe - (bRe * Lre - bIm * Lim);
            float Dim = aIm - (bRe * Lim + bIm * Lre);
            float inv = 1.f / (Dre * Dre + Dim * Dim);
            float eRe = Dre * inv, eIm = -Dim * inv;   // 1/D_n
            float cRe = sCre[n], cIm = -sCim[n];
            float t1Re = cRe * eRe - cIm * eIm, t1Im = cRe * eIm + cIm * eRe;
            float qRe = sPre[n], qIm = -sPim[n];
            float t2Re = qRe * eRe - qIm * eIm, t2Im = qRe * eIm + qIm * eRe;
            float BRe = sBre[n], BIm = sBim[n], PRe = sPre[n], PIm = sPim[n];
            cBx += t1Re * BRe - t1Im * BIm; cBy += t1Re * BIm + t1Im * BRe;
            cPx += t1Re * PRe - t1Im * PIm; cPy += t1Re * PIm + t1Im * PRe;
            pBx += t2Re * BRe - t2Im * BIm; pBy += t2Re * BIm + t2Im * BRe;
            pPx += t2Re * PRe - t2Im * PIm; pPy += t2Re * PIm + t2Im * PRe;
        }
        float denx = 1.f + (bRe * pPx - bIm * pPy);
        float deny = (bRe * pPy + bIm * pPx);
        float bcPx = bRe * cPx - bIm * cPy;
        float bcPy = bRe * cPy + bIm * cPx;
        float numx = bcPx * pBx - bcPy * pBy;
        float numy = bcPx * pBy + bcPy * pBx;
        float dinv = 1.f / (denx * denx + deny * deny);
        float corx = (numx * denx + numy * deny) * dinv;
        float cory = (numy * denx - numx * deny) * dinv;
        g_khat[j] = { 2.f * (cBx - corx), 2.f * (cBy - cory) };
    }
}

// ---------------- Re(k_t) via Hermitian-symmetrized direct IDFT ----------------
__global__ __launch_bounds__(256) void k_ifft() {
    int tid = threadIdx.x;
    int l = tid & 63;
    int t = blockIdx.x * 4 + (tid >> 6);  // 512 blocks x 4 waves = 2048 t's
    float acc = 0.f;
#pragma unroll
    for (int i = 0; i < 16; i++) {
        int j = l + 64 * i;  // 0..1023
        cplx a = g_khat[j];
        cplx b = g_khat[(2048 - j) & 2047];
        float re = 0.5f * (a.x + b.x);
        float im = 0.5f * (a.y - b.y);
        int idx = (j * t) & 2047;
        float s, c;
        __sincosf(0.00306796157577128245f * idx, &s, &c);
        float wgt = (j == 0) ? 1.f : 2.f;
        acc += wgt * (re * c - im * s);
    }
    if (l == 0) acc += (1 - 2 * (t & 1)) * g_khat[1024].x;
#pragma unroll
    for (int off = 1; off < 64; off <<= 1) acc += __shfl_xor(acc, off);
    if (l == 0) g_k[t] = acc * (1.f / 2048.f);
}

// ---------------- build 32 distinct diagonal tiles: Td[d][r][c] = k[64d + r - c] ----------------
__global__ __launch_bounds__(256) void build_Td() {
    int gid = blockIdx.x * 256 + threadIdx.x;  // 64 blocks -> 16384 threads
    int o = gid * 8;                           // 131072 elements total
    int d = o >> 12, rem = o & 4095;
    int r = rem >> 6, c0 = rem & 63;
    int base = d * 64 + r - c0;
    u16x8 v;
#pragma unroll
    for (int q = 0; q < 8; q++) {
        int idx = base - q;
        v[q] = (idx >= 0) ? f2bf(g_k[idx]) : (u16)0;
    }
    *(u16x8*)&g_Td[o] = v;
}

// ---------------- conv GEMM: Y = T @ X (triangular, A from L2-resident Td) ----------------
__global__ __launch_bounds__(256) void conv_gemm() {
    __shared__ __align__(16) u16 As[64 * 64];
    __shared__ __align__(16) u16 Bs[64 * 64];
    int tid = threadIdx.x, l = tid & 63, w = tid >> 6;
    int wm = w >> 1, wn = w & 1;
    int bm = blockIdx.x >> 3, bn = blockIdx.x & 7;  // 32 x 8
    f32x4 acc[2][2] = {};
    int nkb = bm + 1;  // triangular: diagonals d = bm-kb >= 0
    int row0 = tid >> 3, kc0 = tid & 7;
    int row1 = row0 + 32;
    const u16* arow0 = &g_Td[bm * 4096 + row0 * 64 + kc0 * 8];  // step: -4096 per kb
    const u16* arow1 = &g_Td[bm * 4096 + row1 * 64 + kc0 * 8];
    const u16* brow0 = &g_Xt[(bn * 64 + row0) * L_SEQ + kc0 * 8];  // step: +64 per kb
    const u16* brow1 = &g_Xt[(bn * 64 + row1) * L_SEQ + kc0 * 8];
    int sa0 = row0 * 8 + (kc0 ^ (row0 & 7));
    int sa1 = row1 * 8 + (kc0 ^ (row1 & 7));
    // depth-2 prefetch ring (two named slots, no runtime indexing)
    u32x4 raA0 = *(const u32x4*)arow0;
    u32x4 raA1 = *(const u32x4*)arow1;
    u32x4 rbA0 = *(const u32x4*)brow0;
    u32x4 rbA1 = *(const u32x4*)brow1;
    int off2 = (nkb > 1) ? 1 : 0;
    u32x4 raB0 = *(const u32x4*)(arow0 - off2 * 4096);
    u32x4 raB1 = *(const u32x4*)(arow1 - off2 * 4096);
    u32x4 rbB0 = *(const u32x4*)(brow0 + off2 * 64);
    u32x4 rbB1 = *(const u32x4*)(brow1 + off2 * 64);

#define CONV_COMPUTE                                                         \
    _Pragma("unroll")                                                        \
    for (int ks = 0; ks < 2; ks++) {                                         \
        s16x8 af[2], bf[2];                                                  \
        _Pragma("unroll")                                                    \
        for (int m = 0; m < 2; m++) {                                        \
            int row = wm * 32 + m * 16 + (l & 15);                           \
            int chunk = (ks * 4 + (l >> 4)) ^ (row & 7);                     \
            af[m] = *(const s16x8*)&As[row * 64 + chunk * 8];                \
        }                                                                    \
        _Pragma("unroll")                                                    \
        for (int n = 0; n < 2; n++) {                                        \
            int col = wn * 32 + n * 16 + (l & 15);                           \
            int chunk = (ks * 4 + (l >> 4)) ^ (col & 7);                     \
            bf[n] = *(const s16x8*)&Bs[col * 64 + chunk * 8];                \
        }                                                                    \
        _Pragma("unroll")                                                    \
        for (int m = 0; m < 2; m++)                                          \
            _Pragma("unroll")                                                \
            for (int n = 0; n < 2; n++)                                      \
                acc[m][n] = __builtin_amdgcn_mfma_f32_16x16x32_bf16(         \
                    af[m], bf[n], acc[m][n], 0, 0, 0);                       \
    }

#define CONV_STEP(RA0, RA1, RB0, RB1)                                       \
    {                                                                        \
        __syncthreads();                                                     \
        ((u32x4*)As)[sa0] = RA0;                                             \
        ((u32x4*)As)[sa1] = RA1;                                             \
        ((u32x4*)Bs)[sa0] = RB0;                                             \
        ((u32x4*)Bs)[sa1] = RB1;                                             \
        if (kb + 2 < nkb) {                                                  \
            RA0 = *(const u32x4*)(arow0 - (kb + 2) * 4096);                  \
            RA1 = *(const u32x4*)(arow1 - (kb + 2) * 4096);                  \
            RB0 = *(const u32x4*)(brow0 + (kb + 2) * 64);                    \
            RB1 = *(const u32x4*)(brow1 + (kb + 2) * 64);                    \
        }                                                                    \
        __syncthreads();                                                     \
        CONV_COMPUTE;                                                        \
        kb++;                                                                \
    }

    int kb = 0;
    while (true) {
        CONV_STEP(raA0, raA1, rbA0, rbA1);
        if (kb >= nkb) break;
        CONV_STEP(raB0, raB1, rbB0, rbB1);
        if (kb >= nkb) break;
    }
#undef CONV_STEP
#undef CONV_COMPUTE
#pragma unroll
    for (int m = 0; m < 2; m++)
#pragma unroll
        for (int n = 0; n < 2; n++)
#pragma unroll
            for (int r4 = 0; r4 < 4; r4++) {
                int row = bm * 64 + wm * 32 + m * 16 + (l >> 4) * 4 + r4;
                int col = bn * 64 + wn * 32 + n * 16 + (l & 15);
                float y = acc[m][n][r4];
                float u = 1.5957691216057308f * (y + 0.044715f * y * y * y);
                float th = 1.f - 2.f / (__expf(u) + 1.f);
                g_H[row * HID + col] = f2bf(0.5f * y * (1.f + th));
            }
}

// ---------------- FFN: out = x + (H@W1^T + b1) * sigmoid(H@W2^T + b2) ----------------
__global__ __launch_bounds__(256) void ffn_gemm(const float* x, const float* b1,
                                                const float* b2, float* out) {
    __shared__ __align__(16) u16 As[64 * 64];
    __shared__ __align__(16) u16 B1s[64 * 64];
    __shared__ __align__(16) u16 B2s[64 * 64];
    int tid = threadIdx.x, l = tid & 63, w = tid >> 6;
    int wm = w >> 1, wn = w & 1;
    int bm = blockIdx.x >> 3, bn = blockIdx.x & 7;  // 32 x 8
    f32x4 acc1[2][2] = {}, acc2[2][2] = {};
    int row0 = tid >> 3, kc0 = tid & 7;
    int row1 = (256 + tid) >> 3;
    const u16* arow0 = &g_H[(bm * 64 + row0) * HID + kc0 * 8];
    const u16* arow1 = &g_H[(bm * 64 + row1) * HID + kc0 * 8];
    const u16* b1row0 = &g_W1[(bn * 64 + row0) * HID + kc0 * 8];
    const u16* b1row1 = &g_W1[(bn * 64 + row1) * HID + kc0 * 8];
    const u16* b2row0 = &g_W2[(bn * 64 + row0) * HID + kc0 * 8];
    const u16* b2row1 = &g_W2[(bn * 64 + row1) * HID + kc0 * 8];
    int sa0 = row0 * 8 + (kc0 ^ (row0 & 7));
    int sa1 = row1 * 8 + (kc0 ^ (row1 & 7));
    // depth-2 prefetch ring: sets [0] and [1] (fully unrolled loop -> static idx)
    u32x4 rA0[2], rA1[2], rB10[2], rB11[2], rB20[2], rB21[2];
    rA0[0] = *(const u32x4*)arow0;           rA0[1] = *(const u32x4*)(arow0 + 64);
    rA1[0] = *(const u32x4*)arow1;           rA1[1] = *(const u32x4*)(arow1 + 64);
    rB10[0] = *(const u32x4*)b1row0;         rB10[1] = *(const u32x4*)(b1row0 + 64);
    rB11[0] = *(const u32x4*)b1row1;         rB11[1] = *(const u32x4*)(b1row1 + 64);
    rB20[0] = *(const u32x4*)b2row0;         rB20[1] = *(const u32x4*)(b2row0 + 64);
    rB21[0] = *(const u32x4*)b2row1;         rB21[1] = *(const u32x4*)(b2row1 + 64);
#pragma unroll
    for (int kb = 0; kb < 8; kb++) {
        const int cur = kb & 1;
        __syncthreads();
        ((u32x4*)As)[sa0] = rA0[cur];
        ((u32x4*)As)[sa1] = rA1[cur];
        ((u32x4*)B1s)[sa0] = rB10[cur];
        ((u32x4*)B1s)[sa1] = rB11[cur];
        ((u32x4*)B2s)[sa0] = rB20[cur];
        ((u32x4*)B2s)[sa1] = rB21[cur];
        if (kb + 2 < 8) {
            int k0 = (kb + 2) * 64;
            rA0[cur] = *(const u32x4*)(arow0 + k0);
            rA1[cur] = *(const u32x4*)(arow1 + k0);
            rB10[cur] = *(const u32x4*)(b1row0 + k0);
            rB11[cur] = *(const u32x4*)(b1row1 + k0);
            rB20[cur] = *(const u32x4*)(b2row0 + k0);
            rB21[cur] = *(const u32x4*)(b2row1 + k0);
        }
        __syncthreads();
#pragma unroll
        for (int ks = 0; ks < 2; ks++) {
            s16x8 af[2], b1f[2], b2f[2];
#pragma unroll
            for (int m = 0; m < 2; m++) {
                int row = wm * 32 + m * 16 + (l & 15);
                int chunk = (ks * 4 + (l >> 4)) ^ (row & 7);
                af[m] = *(const s16x8*)&As[row * 64 + chunk * 8];
            }
#pragma unroll
            for (int n = 0; n < 2; n++) {
                int col = wn * 32 + n * 16 + (l & 15);
                int chunk = (ks * 4 + (l >> 4)) ^ (col & 7);
                b1f[n] = *(const s16x8*)&B1s[col * 64 + chunk * 8];
                b2f[n] = *(const s16x8*)&B2s[col * 64 + chunk * 8];
            }
#pragma unroll
            for (int m = 0; m < 2; m++)
#pragma unroll
                for (int n = 0; n < 2; n++) {
                    acc1[m][n] = __builtin_amdgcn_mfma_f32_16x16x32_bf16(af[m], b1f[n], acc1[m][n], 0, 0, 0);
                    acc2[m][n] = __builtin_amdgcn_mfma_f32_16x16x32_bf16(af[m], b2f[n], acc2[m][n], 0, 0, 0);
                }
        }
    }
#pragma unroll
    for (int m = 0; m < 2; m++)
#pragma unroll
        for (int n = 0; n < 2; n++)
#pragma unroll
            for (int r4 = 0; r4 < 4; r4++) {
                int row = bm * 64 + wm * 32 + m * 16 + (l >> 4) * 4 + r4;
                int col = bn * 64 + wn * 32 + n * 16 + (l & 15);
                float g1 = acc1[m][n][r4] + b1[col];
                float g2 = acc2[m][n][r4] + b2[col];
                float sg = 1.f / (1.f + __expf(-g2));
                out[row * HID + col] = x[row * HID + col] + g1 * sg;
            }
}

extern "C" void kernel_launch(void* const* d_in, const int* in_sizes, int n_in,
                              void* d_out, int out_size, void* d_ws, size_t ws_size,
                              hipStream_t stream) {
    const float* x = (const float*)d_in[0];
    const float* lre = (const float*)d_in[1];
    const float* lim = (const float*)d_in[2];
    const float* pre = (const float*)d_in[3];
    const float* pim = (const float*)d_in[4];
    const float* bre = (const float*)d_in[5];
    const float* bim = (const float*)d_in[6];
    const float* cre = (const float*)d_in[7];
    const float* cim = (const float*)d_in[8];
    const float* lstep = (const float*)d_in[9];
    const float* w1 = (const float*)d_in[10];
    const float* b1 = (const float*)d_in[11];
    const float* w2 = (const float*)d_in[12];
    const float* b2 = (const float*)d_in[13];
    float* out = (float*)d_out;

    fused_convert<<<776, 256, 0, stream>>>(x, w1, w2, lre, lim, pre, pim,
                                           bre, bim, cre, cim, lstep);
    k_ifft<<<512, 256, 0, stream>>>();
    build_Td<<<64, 256, 0, stream>>>();
    conv_gemm<<<256, 256, 0, stream>>>();
    ffn_gemm<<<256, 256, 0, stream>>>(x, b1, b2, out);
}